// Round 1
// baseline (379.192 us; speedup 1.0000x reference)
//
#include <hip/hip_runtime.h>
#include <math.h>

// Codebook argmin via split-bf16 MFMA: B=16, K=512, C=512, H=W=64.
// cross = xh*ch + xh*cl + xl*ch  (3x v_mfma_f32_32x32x16_bf16), error ~1.5e-4.
// Block: 512 clusters (M) x 64 pixels (N); wave = 4 m-tiles x 2 n-tiles.
// R1: 2-phase double-buffered pipeline (T3-minimum): stage chunk i+1
// (global_load_lds cs + x->reg) BEFORE computing chunk i; the compiler's
// vmcnt(0)-at-barrier then lands after a full MFMA phase instead of
// serializing staging latency every chunk.
// Epilogue: per-lane in-register top-2 over 64 clusters (C/D col = pixel),
// 8-slot LDS combine; near-ties (gap < MARGIN) re-checked in fp64.

#define NK   512
#define NC   512
#define NHW  4096
#define MARGIN 0.02f

typedef unsigned short u16;
typedef __attribute__((ext_vector_type(8)))  short  short8;
typedef __attribute__((ext_vector_type(8)))  unsigned short ushort8;
typedef __attribute__((ext_vector_type(16))) float  f32x16;

__device__ __forceinline__ u16 f2bf(float f) {
    unsigned u = __builtin_bit_cast(unsigned, f);
    u += 0x7FFFu + ((u >> 16) & 1u);          // round-to-nearest-even bf16
    return (u16)(u >> 16);
}
__device__ __forceinline__ float bf2f(u16 h) {
    unsigned u = ((unsigned)h) << 16;
    return __builtin_bit_cast(float, u);
}

// Pack cluster centers into MFMA A-operand fragment order (hi & lo planes) and
// compute 0.5*c_sq. ws layout: wcc[chunk 32][unit 32][lane 64][8 bf16];
// unit u<16 -> hi of m-tile u, u>=16 -> lo of m-tile u-16.
__global__ __launch_bounds__(64) void prep_pack(const float* __restrict__ cc,
                                                u16* __restrict__ wcc,
                                                float* __restrict__ shalf) {
    const int k    = blockIdx.x;
    const int lane = threadIdx.x;      // 64 j-groups of 8 channels
    const int c0   = lane * 8;
    const float* row = cc + (size_t)k * NC + c0;
    ushort8 hi, lo;
    float sum = 0.f;
    #pragma unroll
    for (int i = 0; i < 8; ++i) {
        float v = row[i];
        sum = fmaf(v, v, sum);
        u16 h = f2bf(v);
        hi[i] = h;
        lo[i] = f2bf(v - bf2f(h));
    }
    const int ch = c0 >> 4;            // 16-channel chunk
    const int kh = (c0 >> 3) & 1;      // which 8-chan half of the chunk
    const int mt = k >> 5;             // m-tile
    const int ls = (k & 31) + 32 * kh; // lane slot in fragment
    *(ushort8*)(wcc + ((size_t)(ch * 32 + mt)      * 64 + ls) * 8) = hi;
    *(ushort8*)(wcc + ((size_t)(ch * 32 + 16 + mt) * 64 + ls) * 8) = lo;
    #pragma unroll
    for (int off = 32; off > 0; off >>= 1) sum += __shfl_down(sum, off, 64);
    if (lane == 0) shalf[k] = 0.5f * sum;
}

__global__ __launch_bounds__(256, 2) void codebook_mfma(
        const float* __restrict__ x,
        const float* __restrict__ cc,
        const u16* __restrict__ wcc,
        const float* __restrict__ shalf,
        int* __restrict__ out)
{
    __shared__ __align__(16) u16 cs[2][32 * 512];   // 2 x 32KB cluster frags (dbuf)
    __shared__ __align__(16) u16 xsm[2][4 * 512];   // 2 x 4KB x frags (dbuf)
    __shared__ float sh_s[NK];
    __shared__ int   flagsh[64];
    __shared__ int   bestk_sh[64];

    const int tid  = threadIdx.x;
    const int w    = tid >> 6;
    const int lane = tid & 63;

    const int gp0 = blockIdx.x * 64;             // 4096 % 64 == 0: no batch crossing
    const float* xb = x + (size_t)(gp0 >> 12) * (NC * NHW) + (gp0 & (NHW - 1));

    sh_s[tid]       = shalf[tid];
    sh_s[tid + 256] = shalf[tid + 256];

    f32x16 acc[4][2] = {};

    // x staging assignment: pixel p, chunk-half kh, j-quarter jq (4 channels)
    const int p   = tid & 63;
    const int xkh = w & 1;
    const int jq  = w >> 1;
    const int xoff_hi = ((0 * 2 + (p >> 5)) * 64 + ((p & 31) + 32 * xkh)) * 8 + jq * 4;
    const int xoff_lo = xoff_hi + 2 * 512;
    const float* xp = xb + (size_t)(xkh * 8 + jq * 4) * NHW + p;

    float fx[4];                                  // x prefetch registers

    // Issue the 4 global x loads for chunk ch (issued BEFORE stage_cs so the
    // compiler can wait for them with a counted vmcnt, not a full drain).
    auto xload = [&](int ch) {
        const float* xc = xp + (size_t)ch * 16 * NHW;
        fx[0] = xc[0];
        fx[1] = xc[NHW];
        fx[2] = xc[2 * NHW];
        fx[3] = xc[3 * NHW];
    };
    // Convert + write the prefetched x into xsm[buf].
    auto xwrite = [&](int buf) {
        u16 h0 = f2bf(fx[0]), h1 = f2bf(fx[1]), h2 = f2bf(fx[2]), h3 = f2bf(fx[3]);
        u16 l0 = f2bf(fx[0] - bf2f(h0)), l1 = f2bf(fx[1] - bf2f(h1));
        u16 l2 = f2bf(fx[2] - bf2f(h2)), l3 = f2bf(fx[3] - bf2f(h3));
        uint2 hv = make_uint2((unsigned)h0 | ((unsigned)h1 << 16),
                              (unsigned)h2 | ((unsigned)h3 << 16));
        uint2 lv = make_uint2((unsigned)l0 | ((unsigned)l1 << 16),
                              (unsigned)l2 | ((unsigned)l3 << 16));
        *(uint2*)&xsm[buf][xoff_hi] = hv;
        *(uint2*)&xsm[buf][xoff_lo] = lv;
    };
    // Async global->LDS DMA of chunk ch's cluster frags into cs[buf].
    auto stage_cs = [&](int ch, int buf) {
        #pragma unroll
        for (int i = 0; i < 8; ++i) {
            const int u = w * 8 + i;
            const u16* g = wcc + ((size_t)(ch * 32 + u) * 64 + lane) * 8;
            __builtin_amdgcn_global_load_lds(
                (const __attribute__((address_space(1))) void*)g,
                (__attribute__((address_space(3))) void*)&cs[buf][u * 512],
                16, 0, 0);
        }
    };
    // One chunk of MFMA work out of buffer buf.
    auto compute = [&](int buf) {
        short8 bh[2], bl[2];
        #pragma unroll
        for (int nt = 0; nt < 2; ++nt) {
            bh[nt] = *(const short8*)&xsm[buf][((0 * 2 + nt) * 64 + lane) * 8];
            bl[nt] = *(const short8*)&xsm[buf][((1 * 2 + nt) * 64 + lane) * 8];
        }
        #pragma unroll
        for (int mt = 0; mt < 4; ++mt) {
            const int gm = w * 4 + mt;
            short8 ah = *(const short8*)&cs[buf][((size_t)gm * 64 + lane) * 8];
            short8 al = *(const short8*)&cs[buf][((size_t)(16 + gm) * 64 + lane) * 8];
            #pragma unroll
            for (int nt = 0; nt < 2; ++nt) {
                acc[mt][nt] = __builtin_amdgcn_mfma_f32_32x32x16_bf16(ah, bh[nt], acc[mt][nt], 0, 0, 0);
                acc[mt][nt] = __builtin_amdgcn_mfma_f32_32x32x16_bf16(al, bh[nt], acc[mt][nt], 0, 0, 0);
                acc[mt][nt] = __builtin_amdgcn_mfma_f32_32x32x16_bf16(ah, bl[nt], acc[mt][nt], 0, 0, 0);
            }
        }
    };

    // ---- prologue: stage chunk 0 into buffer 0 ----
    xload(0);
    stage_cs(0, 0);
    xwrite(0);
    __syncthreads();          // vmcnt(0)+lgkmcnt(0): buf0 ready

    // ---- 2-phase pipelined main loop (15 full double-iterations) ----
    for (int ch = 0; ch < 30; ch += 2) {
        // phase A: compute chunk ch (buf0), stage chunk ch+1 (buf1)
        xload(ch + 1);
        stage_cs(ch + 1, 1);
        compute(0);
        xwrite(1);
        __syncthreads();
        // phase B: compute chunk ch+1 (buf1), stage chunk ch+2 (buf0)
        xload(ch + 2);
        stage_cs(ch + 2, 0);
        compute(1);
        xwrite(0);
        __syncthreads();
    }
    // ch = 30: compute buf0, stage chunk 31 into buf1
    xload(31);
    stage_cs(31, 1);
    compute(0);
    xwrite(1);
    __syncthreads();
    // ch = 31: compute buf1, nothing left to stage
    compute(1);
    __syncthreads();

    // ---- epilogue (overlays cs) ----
    double* dvv    = (double*)cs;            // 2KB
    int*    dii    = (int*)(dvv + 256);      // 1KB
    float*  xcol   = (float*)(dii + 256);    // 2KB
    float*  cand_v = xcol + NC;              // 2KB
    float*  cand_s = cand_v + 512;           // 2KB
    int*    cand_k = (int*)(cand_s + 512);   // 2KB

    const int qb = lane >> 5;
    #pragma unroll
    for (int nt = 0; nt < 2; ++nt) {
        float best = -INFINITY, sec = -INFINITY;
        int bk = 0;
        #pragma unroll
        for (int mt = 0; mt < 4; ++mt) {
            const int kbase = w * 128 + mt * 32 + 4 * qb;
            #pragma unroll
            for (int reg = 0; reg < 16; ++reg) {
                const int k = kbase + (reg & 3) + 8 * (reg >> 2);  // ascending in k
                const float v = acc[mt][nt][reg] - sh_s[k];
                if (v > best) { sec = best; best = v; bk = k; }
                else if (v > sec) sec = v;
            }
        }
        const int pc   = nt * 32 + (lane & 31);
        const int slot = w * 2 + qb;
        cand_v[pc * 8 + slot] = best;
        cand_s[pc * 8 + slot] = sec;
        cand_k[pc * 8 + slot] = bk;
    }
    __syncthreads();

    if (tid < 64) {
        float best = -INFINITY, sec = -INFINITY;
        int bk = 1 << 30;
        #pragma unroll
        for (int s = 0; s < 8; ++s) {
            float v  = cand_v[tid * 8 + s];
            float v2 = cand_s[tid * 8 + s];
            int  kk  = cand_k[tid * 8 + s];
            if (v > best || (v == best && kk < bk)) {
                sec = fmaxf(sec, best);
                best = v; bk = kk;
            } else sec = fmaxf(sec, v);
            sec = fmaxf(sec, v2);
        }
        bestk_sh[tid] = bk;
        flagsh[tid] = (best - sec < MARGIN) ? 1 : 0;
    }
    __syncthreads();

    // fp64 full re-check for near-tie pixels (rare)
    for (int pix = 0; pix < 64; ++pix) {
        if (!flagsh[pix]) continue;              // uniform (LDS) branch
        for (int c = tid; c < NC; c += 256)
            xcol[c] = xb[(size_t)c * NHW + pix];
        __syncthreads();
        double bd = 1e300;
        int bkk = 1 << 30;
        #pragma unroll
        for (int r = 0; r < 2; ++r) {
            const int k = tid + r * 256;
            const float4* crow = (const float4*)(cc + (size_t)k * NC);
            const float4* xc4  = (const float4*)xcol;
            double d = 0.0;
            for (int c4 = 0; c4 < NC / 4; ++c4) {
                float4 cv = crow[c4], xv = xc4[c4];
                double d0 = (double)xv.x - (double)cv.x;
                double d1 = (double)xv.y - (double)cv.y;
                double d2 = (double)xv.z - (double)cv.z;
                double d3 = (double)xv.w - (double)cv.w;
                d = fma(d0, d0, d); d = fma(d1, d1, d);
                d = fma(d2, d2, d); d = fma(d3, d3, d);
            }
            if (d < bd || (d == bd && k < bkk)) { bd = d; bkk = k; }
        }
        dvv[tid] = bd; dii[tid] = bkk;
        __syncthreads();
        for (int srd = 128; srd > 0; srd >>= 1) {
            if (tid < srd) {
                double ov = dvv[tid + srd]; int oi = dii[tid + srd];
                if (ov < dvv[tid] || (ov == dvv[tid] && oi < dii[tid])) {
                    dvv[tid] = ov; dii[tid] = oi;
                }
            }
            __syncthreads();
        }
        if (tid == 0) bestk_sh[pix] = dii[0];
        __syncthreads();
    }

    if (tid < 64) out[gp0 + tid] = bestk_sh[tid];
}

extern "C" void kernel_launch(void* const* d_in, const int* in_sizes, int n_in,
                              void* d_out, int out_size, void* d_ws, size_t ws_size,
                              hipStream_t stream) {
    const float* x  = (const float*)d_in[0];   // (16, 512, 64, 64) f32
    const float* cc = (const float*)d_in[1];   // (1, 512, 512, 1, 1) f32 -> [k][c]
    int* out = (int*)d_out;                    // (16, 1, 64, 64) int32

    float* shalf = (float*)d_ws;               // 512 floats
    u16*   wcc   = (u16*)(shalf + NK);         // 1MB frag-ordered hi/lo bf16

    prep_pack<<<NK, 64, 0, stream>>>(cc, wcc, shalf);
    codebook_mfma<<<(16 * NHW) / 64, 256, 0, stream>>>(x, cc, wcc, shalf, out);
}

// Round 2
// 354.785 us; speedup vs baseline: 1.0688x; 1.0688x over previous
//
#include <hip/hip_runtime.h>
#include <math.h>

// Codebook argmin via split-bf16 MFMA: B=16, K=512, C=512, H=W=64.
// cross = xh*ch + xh*cl + xl*ch  (3x v_mfma_f32_32x32x16_bf16), error ~1.5e-4.
// Block: 512 clusters (M) x 64 pixels (N); wave = 4 m-tiles x 2 n-tiles.
// R2: true T3+T4 pipeline — distinct LDS buffers per phase (cs0/cs1, xs0/xs1)
// so alias analysis can't force vmcnt drains before ds_reads, and manual
// counted s_waitcnt + raw s_barrier so the 4 HBM x-loads stay in flight
// ACROSS the barrier (2-phase-deep x prefetch; 1-phase-deep cluster DMA).
// Steady phase: stage(8 gload_lds) | xload(4) | vmcnt(12) | ds_write x |
// MFMA | vmcnt(4) lgkmcnt(0) | s_barrier.  sched_barrier(0) pins issue
// order so the counted waits are exact.
// Epilogue: per-lane in-register top-2 over 64 clusters (C/D col = pixel),
// 8-slot LDS combine; near-ties (gap < MARGIN) re-checked in fp64.

#define NK   512
#define NC   512
#define NHW  4096
#define MARGIN 0.02f

typedef unsigned short u16;
typedef __attribute__((ext_vector_type(8)))  short  short8;
typedef __attribute__((ext_vector_type(8)))  unsigned short ushort8;
typedef __attribute__((ext_vector_type(16))) float  f32x16;

__device__ __forceinline__ u16 f2bf(float f) {
    unsigned u = __builtin_bit_cast(unsigned, f);
    u += 0x7FFFu + ((u >> 16) & 1u);          // round-to-nearest-even bf16
    return (u16)(u >> 16);
}
__device__ __forceinline__ float bf2f(u16 h) {
    unsigned u = ((unsigned)h) << 16;
    return __builtin_bit_cast(float, u);
}

// Pack cluster centers into MFMA A-operand fragment order (hi & lo planes) and
// compute 0.5*c_sq. ws layout: wcc[chunk 32][unit 32][lane 64][8 bf16];
// unit u<16 -> hi of m-tile u, u>=16 -> lo of m-tile u-16.
__global__ __launch_bounds__(64) void prep_pack(const float* __restrict__ cc,
                                                u16* __restrict__ wcc,
                                                float* __restrict__ shalf) {
    const int k    = blockIdx.x;
    const int lane = threadIdx.x;      // 64 j-groups of 8 channels
    const int c0   = lane * 8;
    const float* row = cc + (size_t)k * NC + c0;
    ushort8 hi, lo;
    float sum = 0.f;
    #pragma unroll
    for (int i = 0; i < 8; ++i) {
        float v = row[i];
        sum = fmaf(v, v, sum);
        u16 h = f2bf(v);
        hi[i] = h;
        lo[i] = f2bf(v - bf2f(h));
    }
    const int ch = c0 >> 4;            // 16-channel chunk
    const int kh = (c0 >> 3) & 1;      // which 8-chan half of the chunk
    const int mt = k >> 5;             // m-tile
    const int ls = (k & 31) + 32 * kh; // lane slot in fragment
    *(ushort8*)(wcc + ((size_t)(ch * 32 + mt)      * 64 + ls) * 8) = hi;
    *(ushort8*)(wcc + ((size_t)(ch * 32 + 16 + mt) * 64 + ls) * 8) = lo;
    #pragma unroll
    for (int off = 32; off > 0; off >>= 1) sum += __shfl_down(sum, off, 64);
    if (lane == 0) shalf[k] = 0.5f * sum;
}

__global__ __launch_bounds__(256, 2) void codebook_mfma(
        const float* __restrict__ x,
        const float* __restrict__ cc,
        const u16* __restrict__ wcc,
        const float* __restrict__ shalf,
        int* __restrict__ out)
{
    // Distinct arrays per buffer: lets alias analysis see that DMA into csN
    // cannot touch ds_reads from csM (no conservative vmcnt before compute).
    __shared__ __align__(16) u16 cs0[32 * 512];   // 32KB cluster frags, buf 0
    __shared__ __align__(16) u16 cs1[32 * 512];   // 32KB cluster frags, buf 1
    __shared__ __align__(16) u16 xs0[4 * 512];    // 4KB x frags, buf 0
    __shared__ __align__(16) u16 xs1[4 * 512];    // 4KB x frags, buf 1
    __shared__ float sh_s[NK];
    __shared__ int   flagsh[64];
    __shared__ int   bestk_sh[64];

    const int tid  = threadIdx.x;
    const int w    = tid >> 6;
    const int lane = tid & 63;

    const int gp0 = blockIdx.x * 64;             // 4096 % 64 == 0: no batch crossing
    const float* xb = x + (size_t)(gp0 >> 12) * (NC * NHW) + (gp0 & (NHW - 1));

    sh_s[tid]       = shalf[tid];
    sh_s[tid + 256] = shalf[tid + 256];

    f32x16 acc[4][2] = {};

    // x staging assignment: pixel p, chunk-half kh, j-quarter jq (4 channels)
    const int p   = tid & 63;
    const int xkh = w & 1;
    const int jq  = w >> 1;
    const int xoff_hi = ((0 * 2 + (p >> 5)) * 64 + ((p & 31) + 32 * xkh)) * 8 + jq * 4;
    const int xoff_lo = xoff_hi + 2 * 512;
    const float* xp = xb + (size_t)(xkh * 8 + jq * 4) * NHW + p;

    float fxa[4], fxb[4];                        // 2-deep x prefetch registers

    auto xload = [&](float* fx, int ch) {
        const float* xc = xp + (size_t)ch * 16 * NHW;
        fx[0] = xc[0];
        fx[1] = xc[NHW];
        fx[2] = xc[2 * NHW];
        fx[3] = xc[3 * NHW];
    };
    auto xwrite = [&](const float* fx, u16* xs) {
        u16 h0 = f2bf(fx[0]), h1 = f2bf(fx[1]), h2 = f2bf(fx[2]), h3 = f2bf(fx[3]);
        u16 l0 = f2bf(fx[0] - bf2f(h0)), l1 = f2bf(fx[1] - bf2f(h1));
        u16 l2 = f2bf(fx[2] - bf2f(h2)), l3 = f2bf(fx[3] - bf2f(h3));
        uint2 hv = make_uint2((unsigned)h0 | ((unsigned)h1 << 16),
                              (unsigned)h2 | ((unsigned)h3 << 16));
        uint2 lv = make_uint2((unsigned)l0 | ((unsigned)l1 << 16),
                              (unsigned)l2 | ((unsigned)l3 << 16));
        *(uint2*)&xs[xoff_hi] = hv;
        *(uint2*)&xs[xoff_lo] = lv;
    };
    auto stage_cs = [&](int ch, u16* dst) {
        #pragma unroll
        for (int i = 0; i < 8; ++i) {
            const int u = w * 8 + i;
            const u16* g = wcc + ((size_t)(ch * 32 + u) * 64 + lane) * 8;
            __builtin_amdgcn_global_load_lds(
                (const __attribute__((address_space(1))) void*)g,
                (__attribute__((address_space(3))) void*)(dst + u * 512),
                16, 0, 0);
        }
    };
    auto compute = [&](const u16* csb, const u16* xsb) {
        short8 bh[2], bl[2];
        #pragma unroll
        for (int nt = 0; nt < 2; ++nt) {
            bh[nt] = *(const short8*)&xsb[((0 * 2 + nt) * 64 + lane) * 8];
            bl[nt] = *(const short8*)&xsb[((1 * 2 + nt) * 64 + lane) * 8];
        }
        #pragma unroll
        for (int mt = 0; mt < 4; ++mt) {
            const int gm = w * 4 + mt;
            short8 ah = *(const short8*)&csb[((size_t)gm * 64 + lane) * 8];
            short8 al = *(const short8*)&csb[((size_t)(16 + gm) * 64 + lane) * 8];
            #pragma unroll
            for (int nt = 0; nt < 2; ++nt) {
                acc[mt][nt] = __builtin_amdgcn_mfma_f32_32x32x16_bf16(ah, bh[nt], acc[mt][nt], 0, 0, 0);
                acc[mt][nt] = __builtin_amdgcn_mfma_f32_32x32x16_bf16(al, bh[nt], acc[mt][nt], 0, 0, 0);
                acc[mt][nt] = __builtin_amdgcn_mfma_f32_32x32x16_bf16(ah, bl[nt], acc[mt][nt], 0, 0, 0);
            }
        }
    };

    // Steady-state phase computing chunk t out of (cs_cur, xs_cur) while
    // staging chunk t+1 -> cs_nxt/xs_nxt and prefetching x of chunk t+2.
    // vmcnt accounting (issue order pinned by sched_barrier(0)):
    //   entry: fx_cur's 4 loads outstanding (oldest)
    //   +8 stage | fence | +4 xload -> 16
    //   vmcnt(12): fx_cur drained        -> xwrite may convert
    //   vmcnt(4):  stage drained, fx_nxt's 4 STAY IN FLIGHT across barrier
    auto phase = [&](int t, u16* cs_cur, u16* cs_nxt, u16* xs_cur, u16* xs_nxt,
                     float* fx_cur, float* fx_nxt) {
        stage_cs(t + 1, cs_nxt);
        __builtin_amdgcn_sched_barrier(0);      // pin: all 8 stage loads first
        xload(fx_nxt, t + 2);
        asm volatile("s_waitcnt vmcnt(12)" ::: "memory");
        xwrite(fx_cur, xs_nxt);
        compute(cs_cur, xs_cur);
        asm volatile("s_waitcnt vmcnt(4) lgkmcnt(0)" ::: "memory");
        __builtin_amdgcn_s_barrier();
        __builtin_amdgcn_sched_barrier(0);
    };

    // ---- prologue ----
    asm volatile("s_waitcnt vmcnt(0)" ::: "memory");  // drain sh_s loads: clean counts
    xload(fxa, 0);                                    // 4 (oldest)
    __builtin_amdgcn_sched_barrier(0);
    stage_cs(0, cs0);                                 // +8 -> 12
    __builtin_amdgcn_sched_barrier(0);
    xload(fxb, 1);                                    // +4 -> 16
    asm volatile("s_waitcnt vmcnt(12)" ::: "memory"); // fxa ready
    xwrite(fxa, xs0);
    asm volatile("s_waitcnt vmcnt(4) lgkmcnt(0)" ::: "memory"); // cs0 DMA done, fxb flying
    __builtin_amdgcn_s_barrier();
    __builtin_amdgcn_sched_barrier(0);

    // ---- main loop: phases 0..29 ----
    for (int t = 0; t < 30; t += 2) {
        phase(t,     cs0, cs1, xs0, xs1, fxb, fxa);   // compute chunk t
        phase(t + 1, cs1, cs0, xs1, xs0, fxa, fxb);   // compute chunk t+1
    }

    // ---- tail: phase 30 (stage 31, no further x prefetch) ----
    stage_cs(31, cs1);                                // fxb(4,oldest) + 8 -> 12
    asm volatile("s_waitcnt vmcnt(8)" ::: "memory");  // fxb (chunk31 x) ready
    xwrite(fxb, xs1);
    compute(cs0, xs0);
    asm volatile("s_waitcnt vmcnt(0) lgkmcnt(0)" ::: "memory");
    __builtin_amdgcn_s_barrier();
    __builtin_amdgcn_sched_barrier(0);

    // ---- phase 31: last compute, nothing to stage ----
    compute(cs1, xs1);
    __syncthreads();

    // ---- epilogue (overlays cs0) ----
    double* dvv    = (double*)cs0;           // 2KB
    int*    dii    = (int*)(dvv + 256);      // 1KB
    float*  xcol   = (float*)(dii + 256);    // 2KB
    float*  cand_v = xcol + NC;              // 2KB
    float*  cand_s = cand_v + 512;           // 2KB
    int*    cand_k = (int*)(cand_s + 512);   // 2KB

    const int qb = lane >> 5;
    #pragma unroll
    for (int nt = 0; nt < 2; ++nt) {
        float best = -INFINITY, sec = -INFINITY;
        int bk = 0;
        #pragma unroll
        for (int mt = 0; mt < 4; ++mt) {
            const int kbase = w * 128 + mt * 32 + 4 * qb;
            #pragma unroll
            for (int reg = 0; reg < 16; ++reg) {
                const int k = kbase + (reg & 3) + 8 * (reg >> 2);  // ascending in k
                const float v = acc[mt][nt][reg] - sh_s[k];
                if (v > best) { sec = best; best = v; bk = k; }
                else if (v > sec) sec = v;
            }
        }
        const int pc   = nt * 32 + (lane & 31);
        const int slot = w * 2 + qb;
        cand_v[pc * 8 + slot] = best;
        cand_s[pc * 8 + slot] = sec;
        cand_k[pc * 8 + slot] = bk;
    }
    __syncthreads();

    if (tid < 64) {
        float best = -INFINITY, sec = -INFINITY;
        int bk = 1 << 30;
        #pragma unroll
        for (int s = 0; s < 8; ++s) {
            float v  = cand_v[tid * 8 + s];
            float v2 = cand_s[tid * 8 + s];
            int  kk  = cand_k[tid * 8 + s];
            if (v > best || (v == best && kk < bk)) {
                sec = fmaxf(sec, best);
                best = v; bk = kk;
            } else sec = fmaxf(sec, v);
            sec = fmaxf(sec, v2);
        }
        bestk_sh[tid] = bk;
        flagsh[tid] = (best - sec < MARGIN) ? 1 : 0;
    }
    __syncthreads();

    // fp64 full re-check for near-tie pixels (rare)
    for (int pix = 0; pix < 64; ++pix) {
        if (!flagsh[pix]) continue;              // uniform (LDS) branch
        for (int c = tid; c < NC; c += 256)
            xcol[c] = xb[(size_t)c * NHW + pix];
        __syncthreads();
        double bd = 1e300;
        int bkk = 1 << 30;
        #pragma unroll
        for (int r = 0; r < 2; ++r) {
            const int k = tid + r * 256;
            const float4* crow = (const float4*)(cc + (size_t)k * NC);
            const float4* xc4  = (const float4*)xcol;
            double d = 0.0;
            for (int c4 = 0; c4 < NC / 4; ++c4) {
                float4 cv = crow[c4], xv = xc4[c4];
                double d0 = (double)xv.x - (double)cv.x;
                double d1 = (double)xv.y - (double)cv.y;
                double d2 = (double)xv.z - (double)cv.z;
                double d3 = (double)xv.w - (double)cv.w;
                d = fma(d0, d0, d); d = fma(d1, d1, d);
                d = fma(d2, d2, d); d = fma(d3, d3, d);
            }
            if (d < bd || (d == bd && k < bkk)) { bd = d; bkk = k; }
        }
        dvv[tid] = bd; dii[tid] = bkk;
        __syncthreads();
        for (int srd = 128; srd > 0; srd >>= 1) {
            if (tid < srd) {
                double ov = dvv[tid + srd]; int oi = dii[tid + srd];
                if (ov < dvv[tid] || (ov == dvv[tid] && oi < dii[tid])) {
                    dvv[tid] = ov; dii[tid] = oi;
                }
            }
            __syncthreads();
        }
        if (tid == 0) bestk_sh[pix] = dii[0];
        __syncthreads();
    }

    if (tid < 64) out[gp0 + tid] = bestk_sh[tid];
}

extern "C" void kernel_launch(void* const* d_in, const int* in_sizes, int n_in,
                              void* d_out, int out_size, void* d_ws, size_t ws_size,
                              hipStream_t stream) {
    const float* x  = (const float*)d_in[0];   // (16, 512, 64, 64) f32
    const float* cc = (const float*)d_in[1];   // (1, 512, 512, 1, 1) f32 -> [k][c]
    int* out = (int*)d_out;                    // (16, 1, 64, 64) int32

    float* shalf = (float*)d_ws;               // 512 floats
    u16*   wcc   = (u16*)(shalf + NK);         // 1MB frag-ordered hi/lo bf16

    prep_pack<<<NK, 64, 0, stream>>>(cc, wcc, shalf);
    codebook_mfma<<<(16 * NHW) / 64, 256, 0, stream>>>(x, cc, wcc, shalf, out);
}